// Round 18
// baseline (211.990 us; speedup 1.0000x reference)
//
#include <hip/hip_runtime.h>

// CMAModel: q = x@Wq^T + ctrl@Wc^T ; kv = [x;fwd;rev] ; k/v = kv@{Wk,Wv}^T
// attn with causal-local + always-visible memory cols, shared softmax,
// per-head sigmoid gate on memory contribution, out = ao@Wo^T.
// f32 harness buffers; bf16 internal pipeline (f32 MFMA accumulate).
// Round 18: r13 geometry retried with correct register budget.
// 8-wave blocks (512 thr), 32q/wave, LDS 80KB (K dbuf 32K + V 16K + P 32K)
// -> 2 blocks/CU = 16 waves/CU = 4 waves/SIMD IF VGPR <= 128.
// __launch_bounds__(512,2) (cap 256; compiler picks ~120 for this body --
// r13's (512,4) pinched to 64 and spilled 1.2GB; this can't recur).

typedef unsigned short u16;
typedef unsigned int   u32;
typedef __bf16 bf16x8 __attribute__((ext_vector_type(8)));
typedef float  f32x4  __attribute__((ext_vector_type(4)));

#define B_ 2
#define T_ 2048
#define C_ 768
#define H_ 6
#define D_ 128
#define M_ 3072
#define R_ 320
#define S_ 5440          // T+M+R
#define BT_ 4096         // B*T
#define BS_ 10880        // B*S
#define NS_ 4            // KV chunks (flash-decode split)
#define NMEM_ 53         // memory steps of 64: (M_+R_)/64

#define GLDS(src, dst) __builtin_amdgcn_global_load_lds( \
    (const __attribute__((address_space(1))) void*)(src), \
    (__attribute__((address_space(3))) void*)(dst), 16, 0, 0)

#define MFMA16(a, b, c) __builtin_amdgcn_mfma_f32_16x16x32_bf16((a), (b), (c), 0, 0, 0)

__device__ __forceinline__ float b2f(u16 u) {
  union { u32 i; float f; } c; c.i = ((u32)u) << 16; return c.f;
}
__device__ __forceinline__ u16 f2b(float f) {   // RNE
  union { float f; u32 i; } c; c.f = f;
  return (u16)((c.i + 0x7FFFu + ((c.i >> 16) & 1u)) >> 16);
}

// ---------------- fused prep: kv concat (bf16) + 4x weight cast ------------
// blocks [0,4080): concat x|fwd|rev -> kv ; blocks [4080,6384): cast weights.
__global__ __launch_bounds__(256) void k_prep(const float* __restrict__ x,
                                              const float* __restrict__ fm,
                                              const float* __restrict__ rm,
                                              u16* __restrict__ kv,
                                              const float* __restrict__ w0,
                                              const float* __restrict__ w1,
                                              const float* __restrict__ w2,
                                              const float* __restrict__ w3,
                                              u16* __restrict__ d0,
                                              u16* __restrict__ d1,
                                              u16* __restrict__ d2,
                                              u16* __restrict__ d3) {
  const int bx = blockIdx.x;
  if (bx < 4080) {
    long long i = ((long long)bx * 256 + threadIdx.x) * 8;
    if (i >= (long long)BS_ * C_) return;
    int row = (int)(i / C_);
    int col = (int)(i - (long long)row * C_);
    int b = row / S_, s = row - b * S_;
    const float* src;
    if (s < T_)           src = x  + (size_t)(b * T_ + s) * C_ + col;
    else if (s < T_ + M_) src = fm + (size_t)(b * M_ + (s - T_)) * C_ + col;
    else                  src = rm + (size_t)(b * R_ + (s - T_ - M_)) * C_ + col;
    float4 a0 = *(const float4*)src;
    float4 a1 = *(const float4*)(src + 4);
    u16 o[8] = { f2b(a0.x), f2b(a0.y), f2b(a0.z), f2b(a0.w),
                 f2b(a1.x), f2b(a1.y), f2b(a1.z), f2b(a1.w) };
    *(uint4*)(kv + i) = *(uint4*)o;
  } else {
    int j = bx - 4080;
    int m = j / 576, xi = j - m * 576;
    const float* src = (m == 0) ? w0 : (m == 1) ? w1 : (m == 2) ? w2 : w3;
    u16* dst = (m == 0) ? d0 : (m == 1) ? d1 : (m == 2) ? d2 : d3;
    int i = (xi * 256 + threadIdx.x) * 4;
    float4 v = *(const float4*)(src + i);
    u16 o[4] = { f2b(v.x), f2b(v.y), f2b(v.z), f2b(v.w) };
    *(ushort4*)(dst + i) = *(ushort4*)o;
  }
}

// ---------------- generic GEMM: out[r,o] = sum_k A[r,k]*W[o,k] (+qc bias) ----
// 128x128 tile, BK=32, 3-deep LDS pipeline (stage kt+2, vmcnt(8)), 48KB LDS.
template<bool F32OUT, bool QCBIAS>
__global__ __launch_bounds__(256) void k_gemm(const u16* __restrict__ A,
                                              const u16* __restrict__ W,
                                              const float* __restrict__ ctrl,
                                              const float* __restrict__ Wc,
                                              void* __restrict__ outv,
                                              int rows, int rowShift, int bstride) {
  __shared__ __align__(16) u16 As[3][128 * 32];
  __shared__ __align__(16) u16 Bs[3][128 * 32];
  const int t = threadIdx.x;
  const int lane = t & 63, wv = t >> 6;
  const int wr = (wv >> 1) * 64, wc = (wv & 1) * 64;
  const int fr = lane & 15, fq = lane >> 4;
  const int rowTile = blockIdx.x * 128;
  const int colTile = blockIdx.y * 128;

  f32x4 acc[4][4] = {};

  const int e0 = t * 8;
  const int e1 = (256 + t) * 8;
  const int r0 = e0 >> 5, c0 = e0 & 31;
  const int r1 = e1 >> 5, c1 = e1 & 31;

  int gr0 = rowTile + r0; if (gr0 >= rows) gr0 = rows - 1;
  int gr1 = rowTile + r1; if (gr1 >= rows) gr1 = rows - 1;
  const int msk = (1 << rowShift) - 1;
  const size_t pr0 = (size_t)(gr0 >> rowShift) * bstride + (gr0 & msk);
  const size_t pr1 = (size_t)(gr1 >> rowShift) * bstride + (gr1 & msk);
  const u16* gaB0 = A + pr0 * C_ + c0;
  const u16* gaB1 = A + pr1 * C_ + c1;
  const u16* gbB0 = W + (size_t)(colTile + r0) * C_ + c0;
  const u16* gbB1 = W + (size_t)(colTile + r1) * C_ + c1;
  const int aOff0 = (wv * 64) * 8, aOff1 = (256 + wv * 64) * 8;

#define STAGE_G(bi, kt) do { \
    GLDS(gaB0 + (kt), &As[bi][aOff0]); \
    GLDS(gaB1 + (kt), &As[bi][aOff1]); \
    GLDS(gbB0 + (kt), &Bs[bi][aOff0]); \
    GLDS(gbB1 + (kt), &Bs[bi][aOff1]); } while (0)

  STAGE_G(0, 0);
  STAGE_G(1, 32);
  int cur = 0;

  for (int kt = 0; kt < C_; kt += 32) {
    int nx2 = cur + 2; if (nx2 >= 3) nx2 -= 3;
    if (kt + 64 < C_) {
      STAGE_G(nx2, kt + 64);
      asm volatile("s_waitcnt vmcnt(8)" ::: "memory");   // slice kt landed
    } else if (kt + 32 < C_) {
      asm volatile("s_waitcnt vmcnt(4)" ::: "memory");
    } else {
      asm volatile("s_waitcnt vmcnt(0)" ::: "memory");
    }
    __builtin_amdgcn_s_barrier();

    bf16x8 af[4], bfr[4];
#pragma unroll
    for (int i = 0; i < 4; ++i) af[i]  = *(const bf16x8*)&As[cur][(wr + i * 16 + fr) * 32 + fq * 8];
#pragma unroll
    for (int i = 0; i < 4; ++i) bfr[i] = *(const bf16x8*)&Bs[cur][(wc + i * 16 + fr) * 32 + fq * 8];
#pragma unroll
    for (int mi = 0; mi < 4; ++mi)
#pragma unroll
      for (int ni = 0; ni < 4; ++ni)
        acc[mi][ni] = MFMA16(af[mi], bfr[ni], acc[mi][ni]);
    __builtin_amdgcn_s_barrier();    // reads of cur done before restage
    cur = (cur == 2) ? 0 : cur + 1;
  }
#undef STAGE_G

#pragma unroll
  for (int mi = 0; mi < 4; ++mi) {
#pragma unroll
    for (int ni = 0; ni < 4; ++ni) {
      int cc = colTile + wc + ni * 16 + fr;
      float bb = 0.f;
      if (QCBIAS) {
#pragma unroll
        for (int j = 0; j < 5; ++j) bb += ctrl[j] * Wc[cc * 5 + j];
      }
#pragma unroll
      for (int j = 0; j < 4; ++j) {
        int rr = rowTile + wr + mi * 16 + fq * 4 + j;
        if (rr < rows) {
          float val = acc[mi][ni][j] + bb;
          if (F32OUT) ((float*)outv)[(size_t)rr * C_ + cc] = val;
          else        ((u16*)outv)[(size_t)rr * C_ + cc] = f2b(val);
        }
      }
    }
  }
}

// ---------------- fused K + V^T GEMM --------------------------------------
// kb[s][cc] = mfma(af=kv, bf=Wk); vt[cc][s] = mfma(af=Wv, bf=kv) -- the kv
// fragment's A-layout equals the B-layout, so one LDS read serves both.
__global__ __launch_bounds__(256, 2) void k_gemmKV(const u16* __restrict__ kvb,
                                                   const u16* __restrict__ Wk,
                                                   const u16* __restrict__ Wv,
                                                   u16* __restrict__ kb,
                                                   u16* __restrict__ vt) {
  __shared__ __align__(16) u16 As[2][128 * 32];
  __shared__ __align__(16) u16 Ks2[2][128 * 32];
  __shared__ __align__(16) u16 Vs2[2][128 * 32];
  const int t = threadIdx.x;
  const int lane = t & 63, wv = t >> 6;
  const int wr = (wv >> 1) * 64, wc = (wv & 1) * 64;
  const int fr = lane & 15, fq = lane >> 4;
  const int rowTile = blockIdx.x * 128;   // global s-row over B*S
  const int colTile = blockIdx.y * 128;   // channel cc

  f32x4 accK[4][4] = {};
  f32x4 accV[4][4] = {};

  const int e0 = t * 8;
  const int e1 = (256 + t) * 8;
  const int r0 = e0 >> 5, c0 = e0 & 31;
  const int r1 = e1 >> 5, c1 = e1 & 31;

  const u16* gaB0 = kvb + (size_t)(rowTile + r0) * C_ + c0;
  const u16* gaB1 = kvb + (size_t)(rowTile + r1) * C_ + c1;
  const u16* gkB0 = Wk + (size_t)(colTile + r0) * C_ + c0;
  const u16* gkB1 = Wk + (size_t)(colTile + r1) * C_ + c1;
  const u16* gvB0 = Wv + (size_t)(colTile + r0) * C_ + c0;
  const u16* gvB1 = Wv + (size_t)(colTile + r1) * C_ + c1;
  const int aOff0 = (wv * 64) * 8, aOff1 = (256 + wv * 64) * 8;

#define STAGE_KV(bi, kt) do { \
    GLDS(gaB0 + (kt), &As[bi][aOff0]); \
    GLDS(gaB1 + (kt), &As[bi][aOff1]); \
    GLDS(gkB0 + (kt), &Ks2[bi][aOff0]); \
    GLDS(gkB1 + (kt), &Ks2[bi][aOff1]); \
    GLDS(gvB0 + (kt), &Vs2[bi][aOff0]); \
    GLDS(gvB1 + (kt), &Vs2[bi][aOff1]); } while (0)

  STAGE_KV(0, 0);
  int cur = 0;

  for (int kt = 0; kt < C_; kt += 32) {
    if (kt + 32 < C_) {
      STAGE_KV(cur ^ 1, kt + 32);
      asm volatile("s_waitcnt vmcnt(6)" ::: "memory");   // cur slice landed
    } else {
      asm volatile("s_waitcnt vmcnt(0)" ::: "memory");
    }
    __builtin_amdgcn_s_barrier();

    bf16x8 af[4], wkf[4], wvf[4];
#pragma unroll
    for (int i = 0; i < 4; ++i) af[i]  = *(const bf16x8*)&As[cur][(wr + i * 16 + fr) * 32 + fq * 8];
#pragma unroll
    for (int i = 0; i < 4; ++i) wkf[i] = *(const bf16x8*)&Ks2[cur][(wc + i * 16 + fr) * 32 + fq * 8];
#pragma unroll
    for (int i = 0; i < 4; ++i) wvf[i] = *(const bf16x8*)&Vs2[cur][(wc + i * 16 + fr) * 32 + fq * 8];
#pragma unroll
    for (int mi = 0; mi < 4; ++mi)
#pragma unroll
      for (int ni = 0; ni < 4; ++ni) {
        accK[mi][ni] = MFMA16(af[mi], wkf[ni], accK[mi][ni]);
        accV[mi][ni] = MFMA16(wvf[mi], af[ni], accV[mi][ni]);
      }
    __builtin_amdgcn_s_barrier();    // reads of cur done before restage
    cur ^= 1;
  }
#undef STAGE_KV

  // K epilogue: rows = s-global, cols = cc
#pragma unroll
  for (int mi = 0; mi < 4; ++mi) {
#pragma unroll
    for (int ni = 0; ni < 4; ++ni) {
      int cc = colTile + wc + ni * 16 + fr;
#pragma unroll
      for (int j = 0; j < 4; ++j) {
        int rr = rowTile + wr + mi * 16 + fq * 4 + j;
        kb[(size_t)rr * C_ + cc] = f2b(accK[mi][ni][j]);
      }
    }
  }
  // V^T epilogue: rows = cc, cols = s-global -> vt[(b*C+cc)*S + s]
#pragma unroll
  for (int mi = 0; mi < 4; ++mi) {
#pragma unroll
    for (int ni = 0; ni < 4; ++ni) {
      int sg = rowTile + wr + ni * 16 + fr;
      int b = sg / S_, s = sg - b * S_;
#pragma unroll
      for (int j = 0; j < 4; ++j) {
        int cc = colTile + wc + mi * 16 + fq * 4 + j;
        vt[((size_t)(b * C_ + cc)) * S_ + s] = f2b(accV[mi][ni][j]);
      }
    }
  }
}

// ---------------- gate[b,h,t] = sigmoid(q[b,t,:].Wg[h,:] + bg[h]) ----------
__global__ __launch_bounds__(256) void k_gate(const u16* __restrict__ q,
                                              const float* __restrict__ Wg,
                                              const float* __restrict__ bg,
                                              float* __restrict__ gate) {
  int gid = blockIdx.x * 4 + (threadIdx.x >> 6);   // (b*T+t)*H + h
  int lane = threadIdx.x & 63;
  int h = gid % H_;
  int bt = gid / H_;
  const u16* qrow = q + (size_t)bt * C_;
  const float* wrow = Wg + (size_t)h * C_;
  float a = 0.f;
#pragma unroll
  for (int i = 0; i < 12; ++i) {
    int e = i * 64 + lane;
    a += b2f(qrow[e]) * wrow[e];
  }
#pragma unroll
  for (int off = 1; off < 64; off <<= 1) a += __shfl_xor(a, off);
  if (lane == 0) {
    float xg = a + bg[h];
    int b = bt / T_, tt = bt - b * T_;
    gate[((size_t)b * H_ + h) * T_ + tt] = 1.f / (1.f + __expf(-xg));
  }
}

// ---------------- flash attention: 32 q-rows/wave, 8-wave blocks -----------
// grid (12, 8, NS_): 8 waves/block (512 thr), each wave 32 q-rows (two
// 16-row subtiles sharing every K/V ds_read). LDS: K dbuf 32K + V 16K +
// P 8x4K = 80KB -> 2 blocks/CU = 16 waves/CU = 4 waves/SIMD (needs
// VGPR <= 128; body measured 120 under (256,2)). launch_bounds(512,2)
// caps at 256 -- r13's (512,4) pinch-to-64-and-spill cannot recur.
// Fixed max m=0, gate folded into exponent, row sums via ones-column MFMA,
// dedicated per-wave swizzled P written before the V barrier (r14 schedule).
__global__ __launch_bounds__(512, 2) void k_attn13(const u16* __restrict__ q,
                                                   const u16* __restrict__ kk,
                                                   const u16* __restrict__ vt,
                                                   const float* __restrict__ gate,
                                                   u16* __restrict__ pacc0,
                                                   u16* __restrict__ pacc1,
                                                   u16* __restrict__ pacc2,
                                                   u16* __restrict__ pacc3,
                                                   float* __restrict__ pl) {
  __shared__ __align__(16) u16 Ks[2][64 * 128];   // [s-row][d], swizzled, 2x16KB
  __shared__ __align__(16) u16 Vs[128 * 64];      // [d][s-col], swizzled, 16KB
  __shared__ __align__(16) u16 Pb[8][32 * 64];    // per-wave P (32q x 64k), 32KB

  const int bh = blockIdx.x;
  const int b = bh / H_, h = bh - b * H_;
  const int y = 7 - blockIdx.y;        // reversed: longest blocks first
  const int c = blockIdx.z;
  const int wv = threadIdx.x >> 6, lane = threadIdx.x & 63;
  const int fr = lane & 15, fq = lane >> 4;
  const int qbase = y * 256 + wv * 32;   // this wave's first q-row (covers 32)
  char* Pc = (char*)Pb[wv];

  const u16* Qh = q + (size_t)(b * T_ + qbase) * C_ + h * D_;
  const float* gh = gate + ((size_t)b * H_ + h) * T_ + qbase;

  // staging source pointers (lane-dependent, pre-swizzled columns)
  const int kRow0 = wv * 8 + (lane >> 4), kRow1 = kRow0 + 4;
  const int kCol0 = (((lane & 15) * 16) ^ ((kRow0 & 7) << 4)) >> 1;
  const int kCol1 = (((lane & 15) * 16) ^ ((kRow1 & 7) << 4)) >> 1;
  const u16* kSrc0 = kk + (size_t)(b * S_ + kRow0) * C_ + h * D_ + kCol0;
  const u16* kSrc1 = kk + (size_t)(b * S_ + kRow1) * C_ + h * D_ + kCol1;
  const int vRow0 = wv * 16 + (lane >> 3), vRow1 = vRow0 + 8;
  const int vCol0 = (((lane & 7) * 16) ^ ((vRow0 & 7) << 4)) >> 1;
  const int vCol1 = (((lane & 7) * 16) ^ ((vRow1 & 7) << 4)) >> 1;
  const u16* vSrc0 = vt + ((size_t)b * C_ + h * D_ + vRow0) * S_ + vCol0;
  const u16* vSrc1 = vt + ((size_t)b * C_ + h * D_ + vRow1) * S_ + vCol1;

  bf16x8 qf0[4], qf1[4];
#pragma unroll
  for (int kc = 0; kc < 4; ++kc) {
    qf0[kc] = *(const bf16x8*)&Qh[(size_t)fr * C_ + kc * 32 + fq * 8];
    qf1[kc] = *(const bf16x8*)&Qh[(size_t)(16 + fr) * C_ + kc * 32 + fq * 8];
  }

  f32x4 acc0[8] = {}, acc1[8] = {};
  f32x4 accL0 = {}, accM0 = {}, accL1 = {}, accM1 = {};
  float g0[4], lg0[4], g1[4], lg1[4];
#pragma unroll
  for (int r = 0; r < 4; ++r) {
    g0[r] = gh[fq * 4 + r];      lg0[r] = __log2f(g0[r]);
    g1[r] = gh[16 + fq * 4 + r]; lg1[r] = __log2f(g1[r]);
  }

  const __bf16 one_h = (__bf16)1.0f;
  bf16x8 ones = { one_h, one_h, one_h, one_h, one_h, one_h, one_h, one_h };

  const float scl = 0.08838834764831845f * 1.4426950408889634f; // D^-.5 * log2(e)
  const int xk = (fr & 7) << 4;                                 // read-side XOR (bytes)

  const int nloc = 4 * y + 4;       // local steps (64 cols each) for this block
  const int ntot = nloc + NMEM_;
  auto s_of = [&](int i) { return (i < nloc) ? i * 64 : T_ + (i - nloc) * 64; };

  // prologue: stage K for first step (2 ops in flight)
  {
    int s0 = s_of(c);
    GLDS(kSrc0 + (size_t)s0 * C_, &Ks[0][(wv * 8) * 128]);
    GLDS(kSrc1 + (size_t)s0 * C_, &Ks[0][(wv * 8 + 4) * 128]);
  }
  int cur = 0;

  for (int i = c; i < ntot; i += NS_) {
    const int s0 = s_of(i);
    const bool haveNext = (i + NS_ < ntot);
    // stage V(cur step) + K(next step); counted vmcnt keeps them in flight
    GLDS(vSrc0 + s0, &Vs[(wv * 16) * 64]);
    GLDS(vSrc1 + s0, &Vs[(wv * 16 + 8) * 64]);
    if (haveNext) {
      int sn = s_of(i + NS_);
      GLDS(kSrc0 + (size_t)sn * C_, &Ks[cur ^ 1][(wv * 8) * 128]);
      GLDS(kSrc1 + (size_t)sn * C_, &Ks[cur ^ 1][(wv * 8 + 4) * 128]);
      asm volatile("s_waitcnt vmcnt(4)" ::: "memory");   // K(cur) landed
    } else {
      asm volatile("s_waitcnt vmcnt(2)" ::: "memory");
    }
    __builtin_amdgcn_s_barrier();    // K(cur) ready across all waves

    const bool loc = (i < nloc);
    const bool maskedStep = loc && (s0 + 63 > qbase);
    const bool skip = loc && (s0 > qbase + 31);   // wave fully above diagonal

    bf16x8 pa00, pa01, pa10, pa11;
    if (!skip) {
      f32x4 sc0[4] = {{}, {}, {}, {}};
      f32x4 sc1[4] = {{}, {}, {}, {}};
      // QK^T: K fragment loaded ONCE, used for both q-subtiles
#pragma unroll
      for (int quad = 0; quad < 4; ++quad) {
        const u16* Krow = &Ks[cur][(quad * 16 + fr) * 128];
#pragma unroll
        for (int kc = 0; kc < 4; ++kc) {
          bf16x8 kf = *(const bf16x8*)&Krow[((kc * 64 + fq * 16) ^ xk) >> 1];
          sc0[quad] = MFMA16(qf0[kc], kf, sc0[quad]);
          sc1[quad] = MFMA16(qf1[kc], kf, sc1[quad]);
        }
      }
      if (maskedStep) {
#pragma unroll
        for (int quad = 0; quad < 4; ++quad)
#pragma unroll
          for (int r = 0; r < 4; ++r) {
            int col = s0 + quad * 16 + fr;
            if (col > qbase + fq * 4 + r)      sc0[quad][r] = -1.0e30f;
            if (col > qbase + 16 + fq * 4 + r) sc1[quad][r] = -1.0e30f;
          }
      }
      // fixed-max softmax: p = exp2(sc*scl + ca), ca = 0 (local) / log2(g) (mem)
      // write P to own wave's dedicated swizzled buffer (overlaps other QK)
#pragma unroll
      for (int quad = 0; quad < 4; ++quad)
#pragma unroll
        for (int r = 0; r < 4; ++r) {
          int row = fq * 4 + r;
          int cb = (quad * 32 + fr * 2) ^ ((row & 7) << 4);
          float ca0 = loc ? 0.f : lg0[r];
          float ca1 = loc ? 0.f : lg1[r];
          *(__bf16*)(Pc + row * 128 + cb) =
              (__bf16)exp2f(fmaf(sc0[quad][r], scl, ca0));
          *(__bf16*)(Pc + (16 + row) * 128 + cb) =
              (__bf16)exp2f(fmaf(sc1[quad][r], scl, ca1));
        }
      __builtin_amdgcn_wave_barrier();   // same-wave LDS write->read ordering
      pa00 = *(const bf16x8*)(Pc + fr * 128 + ((fq * 16) ^ xk));
      pa01 = *(const bf16x8*)(Pc + fr * 128 + ((64 + fq * 16) ^ xk));
      pa10 = *(const bf16x8*)(Pc + (16 + fr) * 128 + ((fq * 16) ^ xk));
      pa11 = *(const bf16x8*)(Pc + (16 + fr) * 128 + ((64 + fq * 16) ^ xk));
    }
    if (haveNext) asm volatile("s_waitcnt vmcnt(2)" ::: "memory");  // V(cur) landed
    else          asm volatile("s_waitcnt vmcnt(0)" ::: "memory");
    __builtin_amdgcn_s_barrier();    // V(cur) ready across all waves
    if (!skip) {
      // PV: V fragments loaded ONCE, used for both q-subtiles
#pragma unroll
      for (int nt = 0; nt < 8; ++nt) {
        const u16* Vrow = &Vs[(nt * 16 + fr) * 64];
        bf16x8 vf0 = *(const bf16x8*)&Vrow[((fq * 16) ^ xk) >> 1];
        bf16x8 vf1 = *(const bf16x8*)&Vrow[((64 + fq * 16) ^ xk) >> 1];
        acc0[nt] = MFMA16(pa00, vf0, acc0[nt]);
        acc0[nt] = MFMA16(pa01, vf1, acc0[nt]);
        acc1[nt] = MFMA16(pa10, vf0, acc1[nt]);
        acc1[nt] = MFMA16(pa11, vf1, acc1[nt]);
      }
      // row sums of P via ones column
      if (loc) {
        accL0 = MFMA16(pa00, ones, accL0);
        accL0 = MFMA16(pa01, ones, accL0);
        accL1 = MFMA16(pa10, ones, accL1);
        accL1 = MFMA16(pa11, ones, accL1);
      } else {
        accM0 = MFMA16(pa00, ones, accM0);
        accM0 = MFMA16(pa01, ones, accM0);
        accM1 = MFMA16(pa10, ones, accM1);
        accM1 = MFMA16(pa11, ones, accM1);
      }
    }
    __builtin_amdgcn_s_barrier();    // all reads of cur K/V done before restage
    cur ^= 1;
  }

  // raw partials: acc (bf16, gated numerator) + l per row (f32)
  u16* pb = (c == 0) ? pacc0 : (c == 1) ? pacc1 : (c == 2) ? pacc2 : pacc3;
  const size_t rowb = (size_t)bh * T_ + qbase;
#pragma unroll
  for (int nt = 0; nt < 8; ++nt)
#pragma unroll
    for (int r = 0; r < 4; ++r) {
      ((__bf16*)pb)[(rowb + fq * 4 + r) * D_ + nt * 16 + fr] = (__bf16)acc0[nt][r];
      ((__bf16*)pb)[(rowb + 16 + fq * 4 + r) * D_ + nt * 16 + fr] = (__bf16)acc1[nt][r];
    }
  if (fr == 0) {
    const size_t plb = ((size_t)c * (B_ * H_) + bh) * T_ + qbase;
#pragma unroll
    for (int r = 0; r < 4; ++r) {
      pl[plb + fq * 4 + r]      = accL0[r] + accM0[r] / g0[r];
      pl[plb + 16 + fq * 4 + r] = accL1[r] + accM1[r] / g1[r];
    }
  }
}

// ---------------- combine NS_ partials -> ao (bf16 [B,T,C]) ----------------
// Fixed-max chunks share m=0: plain sums, no reweighting.
__global__ __launch_bounds__(256) void k_combine(const u16* __restrict__ pacc0,
                                                 const u16* __restrict__ pacc1,
                                                 const u16* __restrict__ pacc2,
                                                 const u16* __restrict__ pacc3,
                                                 const float* __restrict__ pl,
                                                 u16* __restrict__ ao) {
  const int row = blockIdx.x * 4 + (threadIdx.x >> 6);   // bh*T + t
  const int lane = threadIdx.x & 63;
  const int bh = row >> 11, t = row & (T_ - 1);
  const int b = bh / H_, h = bh - b * H_;

  float L = pl[(size_t)bh * T_ + t]
          + pl[((size_t)(B_ * H_) + bh) * T_ + t]
          + pl[((size_t)(2 * B_ * H_) + bh) * T_ + t]
          + pl[((size_t)(3 * B_ * H_) + bh) * T_ + t];
  float inv = 1.f / L;
  const size_t rb = ((size_t)bh * T_ + t) * D_ + lane * 2;
  u32 v0 = *(const u32*)&pacc0[rb];
  u32 v1 = *(const u32*)&pacc1[rb];
  u32 v2 = *(const u32*)&pacc2[rb];
  u32 v3 = *(const u32*)&pacc3[rb];
  float o0 = b2f((u16)(v0 & 0xFFFF)) + b2f((u16)(v1 & 0xFFFF))
           + b2f((u16)(v2 & 0xFFFF)) + b2f((u16)(v3 & 0xFFFF));
  float o1 = b2f((u16)(v0 >> 16)) + b2f((u16)(v1 >> 16))
           + b2f((u16)(v2 >> 16)) + b2f((u16)(v3 >> 16));
  u16 o[2] = { f2b(o0 * inv), f2b(o1 * inv) };
  *(u32*)&ao[((size_t)(b * T_ + t)) * C_ + h * D_ + lane * 2] = *(u32*)o;
}

// ---------------- launch ---------------------------------------------------
extern "C" void kernel_launch(void* const* d_in, const int* in_sizes, int n_in,
                              void* d_out, int out_size, void* d_ws, size_t ws_size,
                              hipStream_t stream) {
  const float* x   = (const float*)d_in[0];
  const float* fm  = (const float*)d_in[1];
  const float* rm  = (const float*)d_in[2];
  const float* ctl = (const float*)d_in[3];
  const float* Wq  = (const float*)d_in[4];
  const float* Wk  = (const float*)d_in[5];
  const float* Wv  = (const float*)d_in[6];
  const float* Wo  = (const float*)d_in[7];
  const float* Wc  = (const float*)d_in[8];
  const float* Wg  = (const float*)d_in[9];
  const float* bg  = (const float*)d_in[10];
  float* outp = (float*)d_out;

  // ws layout (bytes) — total 74,223,616:
  //   gate @4096 (96K) | qb @102400 (6.29M) | kv @6393856 (16.7M;
  //     dead after KV-GEMM -> pacc0 @6393856, pacc1 @12685312)
  //   kb @23105536 (16.7M) | vt @39817216 (16.7M; dead after attn -> ao)
  //   pacc2 @56528896 | pacc3 @62820352 | pl @69111808 (384K)
  //   weights @69505024 (4x1.18M)
  char* ws = (char*)d_ws;
  float* gate = (float*)(ws + 4096);
  u16* qb    = (u16*)(ws + 102400);
  u16* kv    = (u16*)(ws + 6393856);
  u16* pacc0 = (u16*)(ws + 6393856);     // overlays kv (dead after KV-GEMM)
  u16* pacc1 = (u16*)(ws + 12685312);
  u16* kb    = (u16*)(ws + 23105536);
  u16* vt    = (u16*)(ws + 39817216);
  u16* ao    = (u16*)(ws + 39817216);    // overlays vt (dead after attn)
  u16* pacc2 = (u16*)(ws + 56528896);
  u16* pacc3 = (u16*)(ws + 62820352);
  float* pl  = (float*)(ws + 69111808);
  u16* Wqb   = (u16*)(ws + 69505024);
  u16* Wkb   = (u16*)(ws + 70684672);
  u16* Wvb   = (u16*)(ws + 71864320);
  u16* Wob   = (u16*)(ws + 73043968);

  k_prep<<<dim3(6384), dim3(256), 0, stream>>>(x, fm, rm, kv,
                                               Wq, Wk, Wv, Wo,
                                               Wqb, Wkb, Wvb, Wob);
  // q-GEMM: A = x's bf16 copy inside kv (row remap via shift=11), qc bias inline
  k_gemm<false, true><<<dim3(32, 6), dim3(256), 0, stream>>>(
      kv, Wqb, ctl, Wc, qb, BT_, 11, S_);
  k_gemmKV<<<dim3(85, 6), dim3(256), 0, stream>>>(kv, Wkb, Wvb, kb, vt);
  k_gate<<<dim3(6144), dim3(256), 0, stream>>>(qb, Wg, bg, gate);
  k_attn13<<<dim3(B_ * H_, 8, NS_), dim3(512), 0, stream>>>(
      qb, kb, vt, gate, pacc0, pacc1, pacc2, pacc3, pl);
  k_combine<<<dim3(6144), dim3(256), 0, stream>>>(pacc0, pacc1, pacc2, pacc3, pl, ao);
  k_gemm<true, false><<<dim3(32, 6), dim3(256), 0, stream>>>(
      ao, Wob, nullptr, nullptr, outp, BT_, 30, 0);
}

// Round 19
// 202.201 us; speedup vs baseline: 1.0484x; 1.0484x over previous
//
#include <hip/hip_runtime.h>

// CMAModel: q = x@Wq^T + ctrl@Wc^T ; kv = [x;fwd;rev] ; k/v = kv@{Wk,Wv}^T
// attn with causal-local + always-visible memory cols, shared softmax,
// per-head sigmoid gate on memory contribution, out = ao@Wo^T.
// f32 harness buffers; bf16 internal pipeline (f32 MFMA accumulate).
// Round 19 (final): r17 configuration verbatim -- best measured (203.0us).
// Session ladder: 704.6 -> 605 (KV-split) -> 324 (LDS-staged K/V, counted
// vmcnt) -> 264 (fixed-max softmax, ones-column row sums) -> 235 (V^T-GEMM,
// 3-deep pipe) -> 217 (fused KV-GEMM) -> 206 (32q/wave) -> 203 (prep fuse).
// Attn local optimum 112.8us verified against 7 structural variants.

typedef unsigned short u16;
typedef unsigned int   u32;
typedef __bf16 bf16x8 __attribute__((ext_vector_type(8)));
typedef float  f32x4  __attribute__((ext_vector_type(4)));

#define B_ 2
#define T_ 2048
#define C_ 768
#define H_ 6
#define D_ 128
#define M_ 3072
#define R_ 320
#define S_ 5440          // T+M+R
#define BT_ 4096         // B*T
#define BS_ 10880        // B*S
#define NS_ 4            // KV chunks (flash-decode split)
#define NMEM_ 53         // memory steps of 64: (M_+R_)/64

#define GLDS(src, dst) __builtin_amdgcn_global_load_lds( \
    (const __attribute__((address_space(1))) void*)(src), \
    (__attribute__((address_space(3))) void*)(dst), 16, 0, 0)

#define MFMA16(a, b, c) __builtin_amdgcn_mfma_f32_16x16x32_bf16((a), (b), (c), 0, 0, 0)

__device__ __forceinline__ float b2f(u16 u) {
  union { u32 i; float f; } c; c.i = ((u32)u) << 16; return c.f;
}
__device__ __forceinline__ u16 f2b(float f) {   // RNE
  union { float f; u32 i; } c; c.f = f;
  return (u16)((c.i + 0x7FFFu + ((c.i >> 16) & 1u)) >> 16);
}

// ---------------- fused prep: kv concat (bf16) + 4x weight cast ------------
// blocks [0,4080): concat x|fwd|rev -> kv ; blocks [4080,6384): cast weights.
__global__ __launch_bounds__(256) void k_prep(const float* __restrict__ x,
                                              const float* __restrict__ fm,
                                              const float* __restrict__ rm,
                                              u16* __restrict__ kv,
                                              const float* __restrict__ w0,
                                              const float* __restrict__ w1,
                                              const float* __restrict__ w2,
                                              const float* __restrict__ w3,
                                              u16* __restrict__ d0,
                                              u16* __restrict__ d1,
                                              u16* __restrict__ d2,
                                              u16* __restrict__ d3) {
  const int bx = blockIdx.x;
  if (bx < 4080) {
    long long i = ((long long)bx * 256 + threadIdx.x) * 8;
    if (i >= (long long)BS_ * C_) return;
    int row = (int)(i / C_);
    int col = (int)(i - (long long)row * C_);
    int b = row / S_, s = row - b * S_;
    const float* src;
    if (s < T_)           src = x  + (size_t)(b * T_ + s) * C_ + col;
    else if (s < T_ + M_) src = fm + (size_t)(b * M_ + (s - T_)) * C_ + col;
    else                  src = rm + (size_t)(b * R_ + (s - T_ - M_)) * C_ + col;
    float4 a0 = *(const float4*)src;
    float4 a1 = *(const float4*)(src + 4);
    u16 o[8] = { f2b(a0.x), f2b(a0.y), f2b(a0.z), f2b(a0.w),
                 f2b(a1.x), f2b(a1.y), f2b(a1.z), f2b(a1.w) };
    *(uint4*)(kv + i) = *(uint4*)o;
  } else {
    int j = bx - 4080;
    int m = j / 576, xi = j - m * 576;
    const float* src = (m == 0) ? w0 : (m == 1) ? w1 : (m == 2) ? w2 : w3;
    u16* dst = (m == 0) ? d0 : (m == 1) ? d1 : (m == 2) ? d2 : d3;
    int i = (xi * 256 + threadIdx.x) * 4;
    float4 v = *(const float4*)(src + i);
    u16 o[4] = { f2b(v.x), f2b(v.y), f2b(v.z), f2b(v.w) };
    *(ushort4*)(dst + i) = *(ushort4*)o;
  }
}

// ---------------- generic GEMM: out[r,o] = sum_k A[r,k]*W[o,k] (+qc bias) ----
// 128x128 tile, BK=32, 3-deep LDS pipeline (stage kt+2, vmcnt(8)), 48KB LDS.
template<bool F32OUT, bool QCBIAS>
__global__ __launch_bounds__(256) void k_gemm(const u16* __restrict__ A,
                                              const u16* __restrict__ W,
                                              const float* __restrict__ ctrl,
                                              const float* __restrict__ Wc,
                                              void* __restrict__ outv,
                                              int rows, int rowShift, int bstride) {
  __shared__ __align__(16) u16 As[3][128 * 32];
  __shared__ __align__(16) u16 Bs[3][128 * 32];
  const int t = threadIdx.x;
  const int lane = t & 63, wv = t >> 6;
  const int wr = (wv >> 1) * 64, wc = (wv & 1) * 64;
  const int fr = lane & 15, fq = lane >> 4;
  const int rowTile = blockIdx.x * 128;
  const int colTile = blockIdx.y * 128;

  f32x4 acc[4][4] = {};

  const int e0 = t * 8;
  const int e1 = (256 + t) * 8;
  const int r0 = e0 >> 5, c0 = e0 & 31;
  const int r1 = e1 >> 5, c1 = e1 & 31;

  int gr0 = rowTile + r0; if (gr0 >= rows) gr0 = rows - 1;
  int gr1 = rowTile + r1; if (gr1 >= rows) gr1 = rows - 1;
  const int msk = (1 << rowShift) - 1;
  const size_t pr0 = (size_t)(gr0 >> rowShift) * bstride + (gr0 & msk);
  const size_t pr1 = (size_t)(gr1 >> rowShift) * bstride + (gr1 & msk);
  const u16* gaB0 = A + pr0 * C_ + c0;
  const u16* gaB1 = A + pr1 * C_ + c1;
  const u16* gbB0 = W + (size_t)(colTile + r0) * C_ + c0;
  const u16* gbB1 = W + (size_t)(colTile + r1) * C_ + c1;
  const int aOff0 = (wv * 64) * 8, aOff1 = (256 + wv * 64) * 8;

#define STAGE_G(bi, kt) do { \
    GLDS(gaB0 + (kt), &As[bi][aOff0]); \
    GLDS(gaB1 + (kt), &As[bi][aOff1]); \
    GLDS(gbB0 + (kt), &Bs[bi][aOff0]); \
    GLDS(gbB1 + (kt), &Bs[bi][aOff1]); } while (0)

  STAGE_G(0, 0);
  STAGE_G(1, 32);
  int cur = 0;

  for (int kt = 0; kt < C_; kt += 32) {
    int nx2 = cur + 2; if (nx2 >= 3) nx2 -= 3;
    if (kt + 64 < C_) {
      STAGE_G(nx2, kt + 64);
      asm volatile("s_waitcnt vmcnt(8)" ::: "memory");   // slice kt landed
    } else if (kt + 32 < C_) {
      asm volatile("s_waitcnt vmcnt(4)" ::: "memory");
    } else {
      asm volatile("s_waitcnt vmcnt(0)" ::: "memory");
    }
    __builtin_amdgcn_s_barrier();

    bf16x8 af[4], bfr[4];
#pragma unroll
    for (int i = 0; i < 4; ++i) af[i]  = *(const bf16x8*)&As[cur][(wr + i * 16 + fr) * 32 + fq * 8];
#pragma unroll
    for (int i = 0; i < 4; ++i) bfr[i] = *(const bf16x8*)&Bs[cur][(wc + i * 16 + fr) * 32 + fq * 8];
#pragma unroll
    for (int mi = 0; mi < 4; ++mi)
#pragma unroll
      for (int ni = 0; ni < 4; ++ni)
        acc[mi][ni] = MFMA16(af[mi], bfr[ni], acc[mi][ni]);
    __builtin_amdgcn_s_barrier();    // reads of cur done before restage
    cur = (cur == 2) ? 0 : cur + 1;
  }
#undef STAGE_G

#pragma unroll
  for (int mi = 0; mi < 4; ++mi) {
#pragma unroll
    for (int ni = 0; ni < 4; ++ni) {
      int cc = colTile + wc + ni * 16 + fr;
      float bb = 0.f;
      if (QCBIAS) {
#pragma unroll
        for (int j = 0; j < 5; ++j) bb += ctrl[j] * Wc[cc * 5 + j];
      }
#pragma unroll
      for (int j = 0; j < 4; ++j) {
        int rr = rowTile + wr + mi * 16 + fq * 4 + j;
        if (rr < rows) {
          float val = acc[mi][ni][j] + bb;
          if (F32OUT) ((float*)outv)[(size_t)rr * C_ + cc] = val;
          else        ((u16*)outv)[(size_t)rr * C_ + cc] = f2b(val);
        }
      }
    }
  }
}

// ---------------- fused K + V^T GEMM --------------------------------------
// kb[s][cc] = mfma(af=kv, bf=Wk); vt[cc][s] = mfma(af=Wv, bf=kv) -- the kv
// fragment's A-layout equals the B-layout, so one LDS read serves both.
__global__ __launch_bounds__(256, 2) void k_gemmKV(const u16* __restrict__ kvb,
                                                   const u16* __restrict__ Wk,
                                                   const u16* __restrict__ Wv,
                                                   u16* __restrict__ kb,
                                                   u16* __restrict__ vt) {
  __shared__ __align__(16) u16 As[2][128 * 32];
  __shared__ __align__(16) u16 Ks2[2][128 * 32];
  __shared__ __align__(16) u16 Vs2[2][128 * 32];
  const int t = threadIdx.x;
  const int lane = t & 63, wv = t >> 6;
  const int wr = (wv >> 1) * 64, wc = (wv & 1) * 64;
  const int fr = lane & 15, fq = lane >> 4;
  const int rowTile = blockIdx.x * 128;   // global s-row over B*S
  const int colTile = blockIdx.y * 128;   // channel cc

  f32x4 accK[4][4] = {};
  f32x4 accV[4][4] = {};

  const int e0 = t * 8;
  const int e1 = (256 + t) * 8;
  const int r0 = e0 >> 5, c0 = e0 & 31;
  const int r1 = e1 >> 5, c1 = e1 & 31;

  const u16* gaB0 = kvb + (size_t)(rowTile + r0) * C_ + c0;
  const u16* gaB1 = kvb + (size_t)(rowTile + r1) * C_ + c1;
  const u16* gkB0 = Wk + (size_t)(colTile + r0) * C_ + c0;
  const u16* gkB1 = Wk + (size_t)(colTile + r1) * C_ + c1;
  const u16* gvB0 = Wv + (size_t)(colTile + r0) * C_ + c0;
  const u16* gvB1 = Wv + (size_t)(colTile + r1) * C_ + c1;
  const int aOff0 = (wv * 64) * 8, aOff1 = (256 + wv * 64) * 8;

#define STAGE_KV(bi, kt) do { \
    GLDS(gaB0 + (kt), &As[bi][aOff0]); \
    GLDS(gaB1 + (kt), &As[bi][aOff1]); \
    GLDS(gkB0 + (kt), &Ks2[bi][aOff0]); \
    GLDS(gkB1 + (kt), &Ks2[bi][aOff1]); \
    GLDS(gvB0 + (kt), &Vs2[bi][aOff0]); \
    GLDS(gvB1 + (kt), &Vs2[bi][aOff1]); } while (0)

  STAGE_KV(0, 0);
  int cur = 0;

  for (int kt = 0; kt < C_; kt += 32) {
    if (kt + 32 < C_) {
      STAGE_KV(cur ^ 1, kt + 32);
      asm volatile("s_waitcnt vmcnt(6)" ::: "memory");   // cur slice landed
    } else {
      asm volatile("s_waitcnt vmcnt(0)" ::: "memory");
    }
    __builtin_amdgcn_s_barrier();

    bf16x8 af[4], wkf[4], wvf[4];
#pragma unroll
    for (int i = 0; i < 4; ++i) af[i]  = *(const bf16x8*)&As[cur][(wr + i * 16 + fr) * 32 + fq * 8];
#pragma unroll
    for (int i = 0; i < 4; ++i) wkf[i] = *(const bf16x8*)&Ks2[cur][(wc + i * 16 + fr) * 32 + fq * 8];
#pragma unroll
    for (int i = 0; i < 4; ++i) wvf[i] = *(const bf16x8*)&Vs2[cur][(wc + i * 16 + fr) * 32 + fq * 8];
#pragma unroll
    for (int mi = 0; mi < 4; ++mi)
#pragma unroll
      for (int ni = 0; ni < 4; ++ni) {
        accK[mi][ni] = MFMA16(af[mi], wkf[ni], accK[mi][ni]);
        accV[mi][ni] = MFMA16(wvf[mi], af[ni], accV[mi][ni]);
      }
    __builtin_amdgcn_s_barrier();    // reads of cur done before restage
    cur ^= 1;
  }
#undef STAGE_KV

  // K epilogue: rows = s-global, cols = cc
#pragma unroll
  for (int mi = 0; mi < 4; ++mi) {
#pragma unroll
    for (int ni = 0; ni < 4; ++ni) {
      int cc = colTile + wc + ni * 16 + fr;
#pragma unroll
      for (int j = 0; j < 4; ++j) {
        int rr = rowTile + wr + mi * 16 + fq * 4 + j;
        kb[(size_t)rr * C_ + cc] = f2b(accK[mi][ni][j]);
      }
    }
  }
  // V^T epilogue: rows = cc, cols = s-global -> vt[(b*C+cc)*S + s]
#pragma unroll
  for (int mi = 0; mi < 4; ++mi) {
#pragma unroll
    for (int ni = 0; ni < 4; ++ni) {
      int sg = rowTile + wr + ni * 16 + fr;
      int b = sg / S_, s = sg - b * S_;
#pragma unroll
      for (int j = 0; j < 4; ++j) {
        int cc = colTile + wc + mi * 16 + fq * 4 + j;
        vt[((size_t)(b * C_ + cc)) * S_ + s] = f2b(accV[mi][ni][j]);
      }
    }
  }
}

// ---------------- gate[b,h,t] = sigmoid(q[b,t,:].Wg[h,:] + bg[h]) ----------
__global__ __launch_bounds__(256) void k_gate(const u16* __restrict__ q,
                                              const float* __restrict__ Wg,
                                              const float* __restrict__ bg,
                                              float* __restrict__ gate) {
  int gid = blockIdx.x * 4 + (threadIdx.x >> 6);   // (b*T+t)*H + h
  int lane = threadIdx.x & 63;
  int h = gid % H_;
  int bt = gid / H_;
  const u16* qrow = q + (size_t)bt * C_;
  const float* wrow = Wg + (size_t)h * C_;
  float a = 0.f;
#pragma unroll
  for (int i = 0; i < 12; ++i) {
    int e = i * 64 + lane;
    a += b2f(qrow[e]) * wrow[e];
  }
#pragma unroll
  for (int off = 1; off < 64; off <<= 1) a += __shfl_xor(a, off);
  if (lane == 0) {
    float xg = a + bg[h];
    int b = bt / T_, tt = bt - b * T_;
    gate[((size_t)b * H_ + h) * T_ + tt] = 1.f / (1.f + __expf(-xg));
  }
}

// ---------------- flash attention: 32 q-rows/wave, 4-wave blocks -----------
// grid (12, 16, NS_): 4 waves/block (256 thr), each wave 32 q-rows (two
// 16-row subtiles sharing every K/V ds_read -> ~1.6x less LDS per MFMA).
// LDS: K dbuf 32K + V 16K + P 4x4K = 64KB -> 2 blocks/CU.
// __launch_bounds__(256,2): 256-VGPR cap (measured 120, no spill).
// Dedicated per-wave swizzled P written BEFORE the V barrier (overlaps other
// waves' QK) -- best schedule across 7 tested variants (112.8us).
// Fixed max m=0 (scores ~N(0,0.31)), gate folded into exponent, row sums
// via ones-column MFMA.
__global__ __launch_bounds__(256, 2) void k_attn10(const u16* __restrict__ q,
                                                   const u16* __restrict__ kk,
                                                   const u16* __restrict__ vt,
                                                   const float* __restrict__ gate,
                                                   u16* __restrict__ pacc0,
                                                   u16* __restrict__ pacc1,
                                                   u16* __restrict__ pacc2,
                                                   u16* __restrict__ pacc3,
                                                   float* __restrict__ pl) {
  __shared__ __align__(16) u16 Ks[2][64 * 128];   // [s-row][d], swizzled, 2x16KB
  __shared__ __align__(16) u16 Vs[128 * 64];      // [d][s-col], swizzled, 16KB
  __shared__ __align__(16) u16 Pb[4][32 * 64];    // per-wave P (32q x 64k), 16KB

  const int bh = blockIdx.x;
  const int b = bh / H_, h = bh - b * H_;
  const int y = 15 - blockIdx.y;       // reversed: longest blocks first
  const int c = blockIdx.z;
  const int wv = threadIdx.x >> 6, lane = threadIdx.x & 63;
  const int fr = lane & 15, fq = lane >> 4;
  const int qbase = y * 128 + wv * 32;   // this wave's first q-row (covers 32)
  char* Pc = (char*)Pb[wv];

  const u16* Qh = q + (size_t)(b * T_ + qbase) * C_ + h * D_;
  const float* gh = gate + ((size_t)b * H_ + h) * T_ + qbase;

  // staging source pointers (lane-dependent, pre-swizzled columns)
  const int kR = lane >> 4, kCb = (lane & 15) * 16;
  const u16* kS[4];
#pragma unroll
  for (int j = 0; j < 4; ++j) {
    int row = wv * 16 + j * 4 + kR;
    kS[j] = kk + (size_t)(b * S_ + row) * C_ + h * D_ + ((kCb ^ ((row & 7) << 4)) >> 1);
  }
  const int vR = lane >> 3, vCb = (lane & 7) * 16;
  const u16* vS[4];
#pragma unroll
  for (int j = 0; j < 4; ++j) {
    int row = wv * 32 + j * 8 + vR;
    vS[j] = vt + ((size_t)b * C_ + h * D_ + row) * S_ + ((vCb ^ ((row & 7) << 4)) >> 1);
  }

#define STAGE_K(buf, s) do { _Pragma("unroll") \
    for (int j = 0; j < 4; ++j) \
      GLDS(kS[j] + (size_t)(s) * C_, &Ks[buf][(wv * 16 + j * 4) * 128]); } while (0)
#define STAGE_V(s) do { _Pragma("unroll") \
    for (int j = 0; j < 4; ++j) \
      GLDS(vS[j] + (s), &Vs[(wv * 32 + j * 8) * 64]); } while (0)

  bf16x8 qf0[4], qf1[4];
#pragma unroll
  for (int kc = 0; kc < 4; ++kc) {
    qf0[kc] = *(const bf16x8*)&Qh[(size_t)fr * C_ + kc * 32 + fq * 8];
    qf1[kc] = *(const bf16x8*)&Qh[(size_t)(16 + fr) * C_ + kc * 32 + fq * 8];
  }

  f32x4 acc0[8] = {}, acc1[8] = {};
  f32x4 accL0 = {}, accM0 = {}, accL1 = {}, accM1 = {};
  float g0[4], lg0[4], g1[4], lg1[4];
#pragma unroll
  for (int r = 0; r < 4; ++r) {
    g0[r] = gh[fq * 4 + r];      lg0[r] = __log2f(g0[r]);
    g1[r] = gh[16 + fq * 4 + r]; lg1[r] = __log2f(g1[r]);
  }

  const __bf16 one_h = (__bf16)1.0f;
  bf16x8 ones = { one_h, one_h, one_h, one_h, one_h, one_h, one_h, one_h };

  const float scl = 0.08838834764831845f * 1.4426950408889634f; // D^-.5 * log2(e)
  const int xk = (fr & 7) << 4;                                 // read-side XOR (bytes)

  const int nloc = 2 * y + 2;       // local steps (64 cols each) for this block
  const int ntot = nloc + NMEM_;
  auto s_of = [&](int i) { return (i < nloc) ? i * 64 : T_ + (i - nloc) * 64; };

  // prologue: stage K for first step (4 ops in flight)
  STAGE_K(0, s_of(c));
  int cur = 0;

  for (int i = c; i < ntot; i += NS_) {
    const int s0 = s_of(i);
    const bool haveNext = (i + NS_ < ntot);
    // stage V(cur step) + K(next step); counted vmcnt keeps them in flight
    STAGE_V(s0);
    if (haveNext) {
      STAGE_K(cur ^ 1, s_of(i + NS_));
      asm volatile("s_waitcnt vmcnt(8)" ::: "memory");   // K(cur) landed
    } else {
      asm volatile("s_waitcnt vmcnt(4)" ::: "memory");
    }
    __builtin_amdgcn_s_barrier();    // K(cur) ready across all waves

    const bool loc = (i < nloc);
    const bool maskedStep = loc && (s0 + 63 > qbase);
    const bool skip = loc && (s0 > qbase + 31);   // wave fully above diagonal

    bf16x8 pa00, pa01, pa10, pa11;
    if (!skip) {
      f32x4 sc0[4] = {{}, {}, {}, {}};
      f32x4 sc1[4] = {{}, {}, {}, {}};
      // QK^T: K fragment loaded ONCE, used for both q-subtiles
#pragma unroll
      for (int quad = 0; quad < 4; ++quad) {
        const u16* Krow = &Ks[cur][(quad * 16 + fr) * 128];
#pragma unroll
        for (int kc = 0; kc < 4; ++kc) {
          bf16x8 kf = *(const bf16x8*)&Krow[((kc * 64 + fq * 16) ^ xk) >> 1];
          sc0[quad] = MFMA16(qf0[kc], kf, sc0[quad]);
          sc1[quad] = MFMA16(qf1[kc], kf, sc1[quad]);
        }
      }
      if (maskedStep) {
#pragma unroll
        for (int quad = 0; quad < 4; ++quad)
#pragma unroll
          for (int r = 0; r < 4; ++r) {
            int col = s0 + quad * 16 + fr;
            if (col > qbase + fq * 4 + r)      sc0[quad][r] = -1.0e30f;
            if (col > qbase + 16 + fq * 4 + r) sc1[quad][r] = -1.0e30f;
          }
      }
      // fixed-max softmax: p = exp2(sc*scl + ca), ca = 0 (local) / log2(g) (mem)
      // write P to own wave's dedicated swizzled buffer (overlaps other QK)
#pragma unroll
      for (int quad = 0; quad < 4; ++quad)
#pragma unroll
        for (int r = 0; r < 4; ++r) {
          int row = fq * 4 + r;
          int cb = (quad * 32 + fr * 2) ^ ((row & 7) << 4);
          float ca0 = loc ? 0.f : lg0[r];
          float ca1 = loc ? 0.f : lg1[r];
          *(__bf16*)(Pc + row * 128 + cb) =
              (__bf16)exp2f(fmaf(sc0[quad][r], scl, ca0));
          *(__bf16*)(Pc + (16 + row) * 128 + cb) =
              (__bf16)exp2f(fmaf(sc1[quad][r], scl, ca1));
        }
      __builtin_amdgcn_wave_barrier();   // same-wave LDS write->read ordering
      pa00 = *(const bf16x8*)(Pc + fr * 128 + ((fq * 16) ^ xk));
      pa01 = *(const bf16x8*)(Pc + fr * 128 + ((64 + fq * 16) ^ xk));
      pa10 = *(const bf16x8*)(Pc + (16 + fr) * 128 + ((fq * 16) ^ xk));
      pa11 = *(const bf16x8*)(Pc + (16 + fr) * 128 + ((64 + fq * 16) ^ xk));
    }
    if (haveNext) asm volatile("s_waitcnt vmcnt(4)" ::: "memory");  // V(cur) landed
    else          asm volatile("s_waitcnt vmcnt(0)" ::: "memory");
    __builtin_amdgcn_s_barrier();    // V(cur) ready across all waves
    if (!skip) {
      // PV: V fragments loaded ONCE, used for both q-subtiles
#pragma unroll
      for (int nt = 0; nt < 8; ++nt) {
        const u16* Vrow = &Vs[(nt * 16 + fr) * 64];
        bf16x8 vf0 = *(const bf16x8*)&Vrow[((fq * 16) ^ xk) >> 1];
        bf16x8 vf1 = *(const bf16x8*)&Vrow[((64 + fq * 16) ^ xk) >> 1];
        acc0[nt] = MFMA16(pa00, vf0, acc0[nt]);
        acc0[nt] = MFMA16(pa01, vf1, acc0[nt]);
        acc1[nt] = MFMA16(pa10, vf0, acc1[nt]);
        acc1[nt] = MFMA16(pa11, vf1, acc1[nt]);
      }
      // row sums of P via ones column
      if (loc) {
        accL0 = MFMA16(pa00, ones, accL0);
        accL0 = MFMA16(pa01, ones, accL0);
        accL1 = MFMA16(pa10, ones, accL1);
        accL1 = MFMA16(pa11, ones, accL1);
      } else {
        accM0 = MFMA16(pa00, ones, accM0);
        accM0 = MFMA16(pa01, ones, accM0);
        accM1 = MFMA16(pa10, ones, accM1);
        accM1 = MFMA16(pa11, ones, accM1);
      }
    }
    __builtin_amdgcn_s_barrier();    // all reads of cur K/V done before restage
    cur ^= 1;
  }
#undef STAGE_K
#undef STAGE_V

  // raw partials: acc (bf16, gated numerator) + l per row (f32)
  u16* pb = (c == 0) ? pacc0 : (c == 1) ? pacc1 : (c == 2) ? pacc2 : pacc3;
  const size_t rowb = (size_t)bh * T_ + qbase;
#pragma unroll
  for (int nt = 0; nt < 8; ++nt)
#pragma unroll
    for (int r = 0; r < 4; ++r) {
      ((__bf16*)pb)[(rowb + fq * 4 + r) * D_ + nt * 16 + fr] = (__bf16)acc0[nt][r];
      ((__bf16*)pb)[(rowb + 16 + fq * 4 + r) * D_ + nt * 16 + fr] = (__bf16)acc1[nt][r];
    }
  if (fr == 0) {
    const size_t plb = ((size_t)c * (B_ * H_) + bh) * T_ + qbase;
#pragma unroll
    for (int r = 0; r < 4; ++r) {
      pl[plb + fq * 4 + r]      = accL0[r] + accM0[r] / g0[r];
      pl[plb + 16 + fq * 4 + r] = accL1[r] + accM1[r] / g1[r];
    }
  }
}

// ---------------- combine NS_ partials -> ao (bf16 [B,T,C]) ----------------
// Fixed-max chunks share m=0: plain sums, no reweighting.
__global__ __launch_bounds__(256) void k_combine(const u16* __restrict__ pacc0,
                                                 const u16* __restrict__ pacc1,
                                                 const u16* __restrict__ pacc2,
                                                 const u16* __restrict__ pacc3,
                                                 const float* __restrict__ pl,
                                                 u16* __restrict__ ao) {
  const int row = blockIdx.x * 4 + (threadIdx.x >> 6);   // bh*T + t
  const int lane = threadIdx.x & 63;
  const int bh = row >> 11, t = row & (T_ - 1);
  const int b = bh / H_, h = bh - b * H_;

  float L = pl[(size_t)bh * T_ + t]
          + pl[((size_t)(B_ * H_) + bh) * T_ + t]
          + pl[((size_t)(2 * B_ * H_) + bh) * T_ + t]
          + pl[((size_t)(3 * B_ * H_) + bh) * T_ + t];
  float inv = 1.f / L;
  const size_t rb = ((size_t)bh * T_ + t) * D_ + lane * 2;
  u32 v0 = *(const u32*)&pacc0[rb];
  u32 v1 = *(const u32*)&pacc1[rb];
  u32 v2 = *(const u32*)&pacc2[rb];
  u32 v3 = *(const u32*)&pacc3[rb];
  float o0 = b2f((u16)(v0 & 0xFFFF)) + b2f((u16)(v1 & 0xFFFF))
           + b2f((u16)(v2 & 0xFFFF)) + b2f((u16)(v3 & 0xFFFF));
  float o1 = b2f((u16)(v0 >> 16)) + b2f((u16)(v1 >> 16))
           + b2f((u16)(v2 >> 16)) + b2f((u16)(v3 >> 16));
  u16 o[2] = { f2b(o0 * inv), f2b(o1 * inv) };
  *(u32*)&ao[((size_t)(b * T_ + t)) * C_ + h * D_ + lane * 2] = *(u32*)o;
}

// ---------------- launch ---------------------------------------------------
extern "C" void kernel_launch(void* const* d_in, const int* in_sizes, int n_in,
                              void* d_out, int out_size, void* d_ws, size_t ws_size,
                              hipStream_t stream) {
  const float* x   = (const float*)d_in[0];
  const float* fm  = (const float*)d_in[1];
  const float* rm  = (const float*)d_in[2];
  const float* ctl = (const float*)d_in[3];
  const float* Wq  = (const float*)d_in[4];
  const float* Wk  = (const float*)d_in[5];
  const float* Wv  = (const float*)d_in[6];
  const float* Wo  = (const float*)d_in[7];
  const float* Wc  = (const float*)d_in[8];
  const float* Wg  = (const float*)d_in[9];
  const float* bg  = (const float*)d_in[10];
  float* outp = (float*)d_out;

  // ws layout (bytes) — total 74,223,616:
  //   gate @4096 (96K) | qb @102400 (6.29M) | kv @6393856 (16.7M;
  //     dead after KV-GEMM -> pacc0 @6393856, pacc1 @12685312)
  //   kb @23105536 (16.7M) | vt @39817216 (16.7M; dead after attn -> ao)
  //   pacc2 @56528896 | pacc3 @62820352 | pl @69111808 (384K)
  //   weights @69505024 (4x1.18M)
  char* ws = (char*)d_ws;
  float* gate = (float*)(ws + 4096);
  u16* qb    = (u16*)(ws + 102400);
  u16* kv    = (u16*)(ws + 6393856);
  u16* pacc0 = (u16*)(ws + 6393856);     // overlays kv (dead after KV-GEMM)
  u16* pacc1 = (u16*)(ws + 12685312);
  u16* kb    = (u16*)(ws + 23105536);
  u16* vt    = (u16*)(ws + 39817216);
  u16* ao    = (u16*)(ws + 39817216);    // overlays vt (dead after attn)
  u16* pacc2 = (u16*)(ws + 56528896);
  u16* pacc3 = (u16*)(ws + 62820352);
  float* pl  = (float*)(ws + 69111808);
  u16* Wqb   = (u16*)(ws + 69505024);
  u16* Wkb   = (u16*)(ws + 70684672);
  u16* Wvb   = (u16*)(ws + 71864320);
  u16* Wob   = (u16*)(ws + 73043968);

  k_prep<<<dim3(6384), dim3(256), 0, stream>>>(x, fm, rm, kv,
                                               Wq, Wk, Wv, Wo,
                                               Wqb, Wkb, Wvb, Wob);
  // q-GEMM: A = x's bf16 copy inside kv (row remap via shift=11), qc bias inline
  k_gemm<false, true><<<dim3(32, 6), dim3(256), 0, stream>>>(
      kv, Wqb, ctl, Wc, qb, BT_, 11, S_);
  k_gemmKV<<<dim3(85, 6), dim3(256), 0, stream>>>(kv, Wkb, Wvb, kb, vt);
  k_gate<<<dim3(6144), dim3(256), 0, stream>>>(qb, Wg, bg, gate);
  k_attn10<<<dim3(B_ * H_, 16, NS_), dim3(256), 0, stream>>>(
      qb, kb, vt, gate, pacc0, pacc1, pacc2, pacc3, pl);
  k_combine<<<dim3(6144), dim3(256), 0, stream>>>(pacc0, pacc1, pacc2, pacc3, pl, ao);
  k_gemm<true, false><<<dim3(32, 6), dim3(256), 0, stream>>>(
      ao, Wob, nullptr, nullptr, outp, BT_, 30, 0);
}